// Round 11
// baseline (480.439 us; speedup 1.0000x reference)
//
#include <hip/hip_runtime.h>
#include <hip/hip_bf16.h>
#include <math.h>

// Problem dims
#define NB 256
#define NT 512
#define NF 128
#define NCOH 64         // coh_pts
#define NIN 192         // F + coh_pts
#define NBS 384         // 3*bulk_pts
#define NROWS (NB*NT)   // 131072

// Material constants (match fp64->fp32 of reference)
#define C11 1098.9010989010989f
#define C12 329.67032967032966f
#define C33 384.61538461538464f
#define H3G 1253.8461538461538f   // 3*G + HARD

typedef __attribute__((ext_vector_type(8))) short bf16x8;   // 8 bf16 = 4 VGPR
typedef __attribute__((ext_vector_type(4))) float f32x4;    // MFMA acc
typedef __attribute__((ext_vector_type(8))) unsigned short ushort8v;

// s_waitcnt with only vmcnt constrained (expcnt=7, lgkmcnt=15 = no-wait)
#define WAITCNT_VM(N) __builtin_amdgcn_s_waitcnt(0x0F70 | ((N) & 15) | (((N) >> 4) << 14))

// A operand, single bf16. TILED layout: [kchunk 0..5][row][32] so one
// (m-tile, kchunk) stage = 8 KB contiguous.
#define PS ((size_t)NROWS * 32)     // plane stride in ushorts
__device__ unsigned short g_Ahi[6 * PS];
__device__ unsigned short g_Bhi[NBS * NIN];             // D-folded W12 hi
__device__ unsigned short g_Blo[NBS * NIN];             // D-folded W12 lo

static __device__ __forceinline__ unsigned short f2bf(float v) {
    __hip_bfloat16 h = __float2bfloat16(v);
    return *reinterpret_cast<unsigned short*>(&h);
}
static __device__ __forceinline__ float bf2f(unsigned short u) {
    unsigned int x = ((unsigned int)u) << 16;
    return *reinterpret_cast<float*>(&x);
}
static __device__ __forceinline__ void async_copy16(const void* g, void* l) {
    __builtin_amdgcn_global_load_lds(
        (const __attribute__((address_space(1))) unsigned int*)g,
        (__attribute__((address_space(3))) unsigned int*)l, 16, 0, 0);
}

// ---------------------------------------------------------------------------
// K0: fold plane-stress D into W12 and split to bf16 hi/lo.
// ---------------------------------------------------------------------------
__global__ __launch_bounds__(256) void k0_w12(const float* __restrict__ W12)
{
    const int idx = blockIdx.x * 256 + threadIdx.x;   // < 384*192 = 73728
    const int r = idx / NIN, i = idx - r * NIN;
    const int p = r / 3, j = r - 3 * p;
    const float* w = W12 + (size_t)(3 * p) * NIN;
    float v;
    if (j == 0)      v = C11 * w[i]           + C12 * w[NIN + i];
    else if (j == 1) v = C12 * w[i]           + C11 * w[NIN + i];
    else             v = C33 * w[2 * NIN + i];
    unsigned short h = f2bf(v);
    g_Bhi[idx] = h;
    g_Blo[idx] = f2bf(v - bf2f(h));
}

// ---------------------------------------------------------------------------
// KX: x (fp32) -> bf16 into tiled A planes 0..3 (cols 0..127). Coalesced.
// ---------------------------------------------------------------------------
__global__ __launch_bounds__(256) void kx_split(const float* __restrict__ x)
{
    const int idx = blockIdx.x * 256 + threadIdx.x;   // NROWS*16
    const int row = idx >> 4, g = idx & 15;
    const float* src = x + (size_t)row * NF + g * 8;
    float4 v0 = ((const float4*)src)[0];
    float4 v1 = ((const float4*)src)[1];
    ushort8v h;
    h[0] = f2bf(v0.x); h[1] = f2bf(v0.y); h[2] = f2bf(v0.z); h[3] = f2bf(v0.w);
    h[4] = f2bf(v1.x); h[5] = f2bf(v1.y); h[6] = f2bf(v1.z); h[7] = f2bf(v1.w);
    *(ushort8v*)(g_Ahi + (size_t)(g >> 2) * PS + (size_t)row * 32 + (g & 3) * 8) = h;
}

// ---------------------------------------------------------------------------
// K1: jumps = leaky_relu(x @ W11^T + b11); d_new. fp32 GEMM.
// ---------------------------------------------------------------------------
__global__ __launch_bounds__(256, 2) void k1_fc11(
    const float* __restrict__ x, const float* __restrict__ W11,
    const float* __restrict__ b11, float* __restrict__ dnew)
{
    __shared__ float As[16][132];
    __shared__ float Bs[16][128];
    const int tid = threadIdx.x;
    const int row0 = blockIdx.x * 128;
    const int tx = tid & 15, ty = tid >> 4;

    float acc[8][8];
#pragma unroll
    for (int i = 0; i < 8; ++i)
#pragma unroll
        for (int j = 0; j < 8; ++j) acc[i][j] = 0.0f;

    const int lr = tid >> 2;
    const int lk = (tid & 3) * 4;
    const int bn = tid >> 1;
    const int bk = (tid & 1) * 8;

    for (int kc = 0; kc < 8; ++kc) {
        const int k0 = kc * 16;
        float4 a0 = *(const float4*)(x + (size_t)(row0 + lr) * NF + k0 + lk);
        float4 a1 = *(const float4*)(x + (size_t)(row0 + lr + 64) * NF + k0 + lk);
        float4 w0 = *(const float4*)(W11 + (size_t)bn * NF + k0 + bk);
        float4 w1 = *(const float4*)(W11 + (size_t)bn * NF + k0 + bk + 4);
        __syncthreads();
        As[lk+0][lr] = a0.x; As[lk+1][lr] = a0.y; As[lk+2][lr] = a0.z; As[lk+3][lr] = a0.w;
        As[lk+0][lr+64] = a1.x; As[lk+1][lr+64] = a1.y; As[lk+2][lr+64] = a1.z; As[lk+3][lr+64] = a1.w;
        Bs[bk+0][bn] = w0.x; Bs[bk+1][bn] = w0.y; Bs[bk+2][bn] = w0.z; Bs[bk+3][bn] = w0.w;
        Bs[bk+4][bn] = w1.x; Bs[bk+5][bn] = w1.y; Bs[bk+6][bn] = w1.z; Bs[bk+7][bn] = w1.w;
        __syncthreads();
#pragma unroll
        for (int k = 0; k < 16; ++k) {
            float4 av0 = *(const float4*)&As[k][8*ty];
            float4 av1 = *(const float4*)&As[k][8*ty+4];
            float4 bv0 = *(const float4*)&Bs[k][8*tx];
            float4 bv1 = *(const float4*)&Bs[k][8*tx+4];
            float a[8] = {av0.x,av0.y,av0.z,av0.w,av1.x,av1.y,av1.z,av1.w};
            float b[8] = {bv0.x,bv0.y,bv0.z,bv0.w,bv1.x,bv1.y,bv1.z,bv1.w};
#pragma unroll
            for (int i = 0; i < 8; ++i)
#pragma unroll
                for (int j = 0; j < 8; ++j)
                    acc[i][j] = fmaf(a[i], b[j], acc[i][j]);
        }
    }

#pragma unroll
    for (int i = 0; i < 8; ++i) {
        const int row = row0 + 8*ty + i;
        float dnv[4];
#pragma unroll
        for (int jp = 0; jp < 4; ++jp) {
            float z0 = acc[i][2*jp]   + b11[8*tx + 2*jp];
            float z1 = acc[i][2*jp+1] + b11[8*tx + 2*jp+1];
            float jn = fmaxf(z0, 0.0f);
            float js = (z1 > 0.0f) ? z1 : 0.01f * z1;
            float delta = sqrtf(jn*jn + js*js + 1e-12f);
            float dn = 0.1f * (delta - 0.01f) / (fmaxf(delta, 1e-12f) * 0.09f);
            dnv[jp] = fminf(fmaxf(dn, 0.0f), 1.0f);
        }
        float4 dv; dv.x = dnv[0]; dv.y = dnv[1]; dv.z = dnv[2]; dv.w = dnv[3];
        *(float4*)(dnew + (size_t)row * NCOH + 4*tx) = dv;
    }
}

// ---------------------------------------------------------------------------
// K2 (two-phase parallel cummax): k2a segment maxima, k2b carry + rewalk,
// emitting bf16 into tiled A planes 4..5.
// ---------------------------------------------------------------------------
__global__ __launch_bounds__(64) void k2a(const float* __restrict__ d,
                                          float* __restrict__ totals)
{
    const int b = blockIdx.x >> 3, seg = blockIdx.x & 7;
    const int c = threadIdx.x;
    const float* p = d + (size_t)b * NT * NCOH + (size_t)seg * 64 * NCOH + c;
    float m = 0.0f;
#pragma unroll 8
    for (int i = 0; i < 64; ++i) m = fmaxf(m, p[(size_t)i * NCOH]);
    totals[(size_t)(b * 8 + seg) * 64 + c] = m;
}

__global__ __launch_bounds__(64) void k2b(const float* __restrict__ d,
                                          const float* __restrict__ totals)
{
    const int b = blockIdx.x >> 3, seg = blockIdx.x & 7;
    const int c = threadIdx.x;
    float carry = 0.0f;
    for (int s = 0; s < seg; ++s)
        carry = fmaxf(carry, totals[(size_t)(b * 8 + s) * 64 + c]);
    const float* p = d + (size_t)b * NT * NCOH + (size_t)seg * 64 * NCOH + c;
    unsigned short* ah = g_Ahi + (size_t)(4 + (c >> 5)) * PS
                       + (size_t)(b * NT + seg * 64) * 32 + (c & 31);
    float m = carry;
#pragma unroll 8
    for (int i = 0; i < 64; ++i) {
        m = fmaxf(m, p[(size_t)i * NCOH]);
        ah[(size_t)i * 32] = f2bf(m);
    }
}

// ---------------------------------------------------------------------------
// K3: sig_tr = A @ B^T, A single bf16, B hi+lo. A-stationary, triple-buffered,
// vmcnt(6) + raw barrier, ONE barrier per chunk (6 total).
// R11: epilogue writes CHAIN-MAJOR sig_cm[b*128+p][t*3+j] so k4 reads a
// contiguous per-thread stream. Scattered 2B stores, but the block covers
// whole cachelines collectively -> L2 write-combines, HBM bytes unchanged.
// ---------------------------------------------------------------------------
__global__ __launch_bounds__(256) void k3_mfma(unsigned short* __restrict__ sig_cm)
{
    __shared__ unsigned short Ah[3][4096];   // 3 x 8 KB
    __shared__ unsigned short Bh[3][4096];
    __shared__ unsigned short Bl[3][4096];

    const int tid = threadIdx.x;
    const int lane = tid & 63, w = tid >> 6;
    const int m0 = blockIdx.y * 128;
    const int n0 = blockIdx.x * 128;
    const int wm = (w >> 1) * 64, wn = (w & 1) * 64;
    const int fr = lane & 15, fq = lane >> 4;

    f32x4 acc[4][4];
#pragma unroll
    for (int mi = 0; mi < 4; ++mi)
#pragma unroll
        for (int ni = 0; ni < 4; ++ni) acc[mi][ni] = (f32x4){0.f, 0.f, 0.f, 0.f};

    const int off0 = tid * 16;            // bytes [0, 4096)
    const int off1 = tid * 16 + 4096;     // bytes [4096, 8192)
    const int r0 = off0 >> 6, q0 = (off0 >> 4) & 3;   // B addressing
    const int r1 = off1 >> 6, q1 = (off1 >> 4) & 3;

    const char* Abase = (const char*)(g_Ahi + (size_t)m0 * 32);
    const size_t Aplane = PS * 2;         // bytes per plane

#define ISSUE_CHUNK(kc, buf_)                                                   \
    {                                                                           \
        const char* As_ = Abase + (size_t)(kc) * Aplane;                        \
        async_copy16(As_ + off0, (char*)Ah[buf_] + off0);                       \
        async_copy16(As_ + off1, (char*)Ah[buf_] + off1);                       \
        async_copy16(g_Bhi + (size_t)(n0 + r0) * NIN + (kc) * 32 + q0 * 8,      \
                     (char*)Bh[buf_] + off0);                                   \
        async_copy16(g_Bhi + (size_t)(n0 + r1) * NIN + (kc) * 32 + q1 * 8,      \
                     (char*)Bh[buf_] + off1);                                   \
        async_copy16(g_Blo + (size_t)(n0 + r0) * NIN + (kc) * 32 + q0 * 8,      \
                     (char*)Bl[buf_] + off0);                                   \
        async_copy16(g_Blo + (size_t)(n0 + r1) * NIN + (kc) * 32 + q1 * 8,      \
                     (char*)Bl[buf_] + off1);                                   \
    }

    ISSUE_CHUNK(0, 0);

    int buf = 0;
#pragma unroll 1
    for (int c = 0; c < 5; ++c) {
        const int nbuf = (buf == 2) ? 0 : buf + 1;
        ISSUE_CHUNK(c + 1, nbuf);
        WAITCNT_VM(6);
        __builtin_amdgcn_s_barrier();

        bf16x8 a[4], bh[4], bl[4];
#pragma unroll
        for (int mi = 0; mi < 4; ++mi)
            a[mi] = *(bf16x8*)&Ah[buf][(wm + mi * 16 + fr) * 32 + fq * 8];
#pragma unroll
        for (int ni = 0; ni < 4; ++ni) {
            bh[ni] = *(bf16x8*)&Bh[buf][(wn + ni * 16 + fr) * 32 + fq * 8];
            bl[ni] = *(bf16x8*)&Bl[buf][(wn + ni * 16 + fr) * 32 + fq * 8];
        }
#pragma unroll
        for (int mi = 0; mi < 4; ++mi)
#pragma unroll
            for (int ni = 0; ni < 4; ++ni) {
                acc[mi][ni] = __builtin_amdgcn_mfma_f32_16x16x32_bf16(
                    a[mi], bh[ni], acc[mi][ni], 0, 0, 0);
                acc[mi][ni] = __builtin_amdgcn_mfma_f32_16x16x32_bf16(
                    a[mi], bl[ni], acc[mi][ni], 0, 0, 0);
            }
        buf = nbuf;
    }

    WAITCNT_VM(0);
    __builtin_amdgcn_s_barrier();
    {
        bf16x8 a[4], bh[4], bl[4];
#pragma unroll
        for (int mi = 0; mi < 4; ++mi)
            a[mi] = *(bf16x8*)&Ah[buf][(wm + mi * 16 + fr) * 32 + fq * 8];
#pragma unroll
        for (int ni = 0; ni < 4; ++ni) {
            bh[ni] = *(bf16x8*)&Bh[buf][(wn + ni * 16 + fr) * 32 + fq * 8];
            bl[ni] = *(bf16x8*)&Bl[buf][(wn + ni * 16 + fr) * 32 + fq * 8];
        }
#pragma unroll
        for (int mi = 0; mi < 4; ++mi)
#pragma unroll
            for (int ni = 0; ni < 4; ++ni) {
                acc[mi][ni] = __builtin_amdgcn_mfma_f32_16x16x32_bf16(
                    a[mi], bh[ni], acc[mi][ni], 0, 0, 0);
                acc[mi][ni] = __builtin_amdgcn_mfma_f32_16x16x32_bf16(
                    a[mi], bl[ni], acc[mi][ni], 0, 0, 0);
            }
    }
#undef ISSUE_CHUNK

    // epilogue: C/D layout col=lane&15, row=(lane>>4)*4+reg; chain-major bf16
    const int er = fq * 4, ec = fr;
    const int bb = m0 >> 9;                     // batch of this m-tile
    const int tbase = (m0 & 511) + wm + er;     // t of r=0, mi=0
#pragma unroll
    for (int ni = 0; ni < 4; ++ni) {
        const int col = n0 + wn + ni * 16 + ec;
        const int pch = col / 3, j = col - 3 * pch;
        unsigned short* dst = sig_cm + (size_t)(bb * 128 + pch) * (NT * 3) + j;
#pragma unroll
        for (int mi = 0; mi < 4; ++mi)
#pragma unroll
            for (int r = 0; r < 4; ++r)
                dst[(size_t)(tbase + mi * 16 + r) * 3] = f2bf(acc[mi][ni][r]);
    }
}

// ---------------------------------------------------------------------------
// K4: radial-return ep scan. Reads chain-major (contiguous 3 KB/thread,
// ushort8 loads, depth-4-group circular prefetch = 192 B/lane in flight);
// writes row-major for k5 (coalesced across lanes). No barriers.
// ---------------------------------------------------------------------------
__global__ __launch_bounds__(128) void k4_plast(
    const unsigned short* __restrict__ sig_cm, unsigned short* __restrict__ sig_rm)
{
    const int g = blockIdx.x * 128 + threadIdx.x;   // chain id = b*128+p
    const int b = g >> 7, p = g & 127;
    const ushort8v* src = (const ushort8v*)(sig_cm + (size_t)g * (NT * 3));
    unsigned short* dst = sig_rm + (size_t)b * NT * NBS + 3 * p;

    ushort8v rbuf[4][3];
#pragma unroll
    for (int u = 0; u < 4; ++u) {
        rbuf[u][0] = src[u * 3 + 0];
        rbuf[u][1] = src[u * 3 + 1];
        rbuf[u][2] = src[u * 3 + 2];
    }

    float ep = 0.0f;
#pragma unroll 2
    for (int grp = 0; grp < NT / 8; ++grp) {
        const int cur = grp & 3;
        unsigned short u[24];
        *(ushort8v*)&u[0]  = rbuf[cur][0];
        *(ushort8v*)&u[8]  = rbuf[cur][1];
        *(ushort8v*)&u[16] = rbuf[cur][2];
        if (grp + 4 < NT / 8) {
            rbuf[cur][0] = src[(grp + 4) * 3 + 0];
            rbuf[cur][1] = src[(grp + 4) * 3 + 1];
            rbuf[cur][2] = src[(grp + 4) * 3 + 2];
        }
#pragma unroll
        for (int k = 0; k < 8; ++k) {
            const int t = grp * 8 + k;
            float sxx = bf2f(u[3*k]), syy = bf2f(u[3*k+1]), txy = bf2f(u[3*k+2]);
            float seq = sqrtf(sxx*sxx - sxx*syy + syy*syy + 3.0f*txy*txy + 1e-12f);
            float fy = seq - (10.0f + 100.0f * ep);
            float dep = (fy > 0.0f) ? (fy / H3G) : 0.0f;
            ep += dep;
            float scale = (fy > 0.0f) ? ((10.0f + 100.0f * ep) / seq) : 1.0f;
            unsigned short* op = dst + (size_t)t * NBS;
            op[0] = f2bf(sxx * scale); op[1] = f2bf(syy * scale); op[2] = f2bf(txy * scale);
        }
    }
}

// ---------------------------------------------------------------------------
// K5: out = softplus(sig @ W2^T). Row-per-thread, zero cross-lane ops.
// ---------------------------------------------------------------------------
__global__ __launch_bounds__(256) void k5_out(
    const unsigned short* __restrict__ sig16, const float* __restrict__ W2,
    float* __restrict__ out)
{
    __shared__ float W2s[6][NBS];
    const int tid = threadIdx.x;
    for (int i = tid; i < 6 * NBS; i += 256) W2s[i / NBS][i % NBS] = W2[i];
    __syncthreads();

    const int row = blockIdx.x * 256 + tid;
    const ushort8v* sv = (const ushort8v*)(sig16 + (size_t)row * NBS);

    float acc[6] = {0, 0, 0, 0, 0, 0};
#pragma unroll 4
    for (int q = 0; q < NBS / 8; ++q) {
        ushort8v u = sv[q];
        float v[8];
#pragma unroll
        for (int i = 0; i < 8; ++i) v[i] = bf2f(u[i]);
#pragma unroll
        for (int o = 0; o < 6; ++o) {
            float4 w0 = *(const float4*)&W2s[o][8 * q];
            float4 w1 = *(const float4*)&W2s[o][8 * q + 4];
            acc[o] = fmaf(v[0], w0.x, acc[o]); acc[o] = fmaf(v[1], w0.y, acc[o]);
            acc[o] = fmaf(v[2], w0.z, acc[o]); acc[o] = fmaf(v[3], w0.w, acc[o]);
            acc[o] = fmaf(v[4], w1.x, acc[o]); acc[o] = fmaf(v[5], w1.y, acc[o]);
            acc[o] = fmaf(v[6], w1.z, acc[o]); acc[o] = fmaf(v[7], w1.w, acc[o]);
        }
    }

    float res[6];
#pragma unroll
    for (int o = 0; o < 6; ++o) {
        float z = acc[o];
        res[o] = fmaxf(z, 0.0f) + log1pf(expf(-fabsf(z)));
    }
    float* op = out + (size_t)row * 6;
#pragma unroll
    for (int o = 0; o < 6; ++o) op[o] = res[o];
}

// ---------------------------------------------------------------------------
extern "C" void kernel_launch(void* const* d_in, const int* in_sizes, int n_in,
                              void* d_out, int out_size, void* d_ws, size_t ws_size,
                              hipStream_t stream)
{
    const float* x   = (const float*)d_in[0];
    const float* W11 = (const float*)d_in[1];
    const float* b11 = (const float*)d_in[2];
    const float* W12 = (const float*)d_in[3];
    const float* W2  = (const float*)d_in[4];
    float* out = (float*)d_out;

    // ws (224 MB total = R1's proven footprint):
    //   dnew   32 MB @ 0
    //   sig_cm 96 MB @ 32 MB   (totals aliases its first 512 KB — k2a/k2b
    //                           finish before k3 writes sig_cm; same stream)
    //   sig_rm 96 MB @ 128 MB
    float* dnew = (float*)d_ws;
    unsigned short* sig_cm = (unsigned short*)((char*)d_ws + (size_t)32 * 1024 * 1024);
    float* totals          = (float*)((char*)d_ws + (size_t)32 * 1024 * 1024);
    unsigned short* sig_rm = (unsigned short*)((char*)d_ws + (size_t)128 * 1024 * 1024);

    k0_w12<<<(NBS * NIN) / 256, 256, 0, stream>>>(W12);
    kx_split<<<(NROWS * 16) / 256, 256, 0, stream>>>(x);
    k1_fc11<<<NROWS / 128, 256, 0, stream>>>(x, W11, b11, dnew);
    k2a<<<NB * 8, 64, 0, stream>>>(dnew, totals);
    k2b<<<NB * 8, 64, 0, stream>>>(dnew, totals);
    k3_mfma<<<dim3(3, NROWS / 128), 256, 0, stream>>>(sig_cm);
    k4_plast<<<NB, 128, 0, stream>>>(sig_cm, sig_rm);
    k5_out<<<NROWS / 256, 256, 0, stream>>>(sig_rm, W2, out);
}

// Round 12
// 422.618 us; speedup vs baseline: 1.1368x; 1.1368x over previous
//
#include <hip/hip_runtime.h>
#include <hip/hip_bf16.h>
#include <math.h>

// Problem dims
#define NB 256
#define NT 512
#define NF 128
#define NCOH 64         // coh_pts
#define NIN 192         // F + coh_pts
#define NBS 384         // 3*bulk_pts
#define NBSP 512        // padded row: 128 chains x 4 ushorts (j=0..2 + pad)
#define NROWS (NB*NT)   // 131072

// Material constants (match fp64->fp32 of reference)
#define C11 1098.9010989010989f
#define C12 329.67032967032966f
#define C33 384.61538461538464f
#define H3G 1253.8461538461538f   // 3*G + HARD

typedef __attribute__((ext_vector_type(8))) short bf16x8;   // 8 bf16 = 4 VGPR
typedef __attribute__((ext_vector_type(4))) float f32x4;    // MFMA acc
typedef __attribute__((ext_vector_type(4))) unsigned short ushort4v;
typedef __attribute__((ext_vector_type(8))) unsigned short ushort8v;

// s_waitcnt with only vmcnt constrained (expcnt=7, lgkmcnt=15 = no-wait)
#define WAITCNT_VM(N) __builtin_amdgcn_s_waitcnt(0x0F70 | ((N) & 15) | (((N) >> 4) << 14))

// A operand, single bf16. TILED layout: [kchunk 0..5][row][32] so one
// (m-tile, kchunk) stage = 8 KB contiguous.
#define PS ((size_t)NROWS * 32)     // plane stride in ushorts
__device__ unsigned short g_Ahi[6 * PS];
__device__ unsigned short g_Bhi[NBS * NIN];             // D-folded W12 hi
__device__ unsigned short g_Blo[NBS * NIN];             // D-folded W12 lo

static __device__ __forceinline__ unsigned short f2bf(float v) {
    __hip_bfloat16 h = __float2bfloat16(v);
    return *reinterpret_cast<unsigned short*>(&h);
}
static __device__ __forceinline__ float bf2f(unsigned short u) {
    unsigned int x = ((unsigned int)u) << 16;
    return *reinterpret_cast<float*>(&x);
}
static __device__ __forceinline__ void async_copy16(const void* g, void* l) {
    __builtin_amdgcn_global_load_lds(
        (const __attribute__((address_space(1))) unsigned int*)g,
        (__attribute__((address_space(3))) unsigned int*)l, 16, 0, 0);
}

// ---------------------------------------------------------------------------
// K0: fold plane-stress D into W12 and split to bf16 hi/lo.
// ---------------------------------------------------------------------------
__global__ __launch_bounds__(256) void k0_w12(const float* __restrict__ W12)
{
    const int idx = blockIdx.x * 256 + threadIdx.x;   // < 384*192 = 73728
    const int r = idx / NIN, i = idx - r * NIN;
    const int p = r / 3, j = r - 3 * p;
    const float* w = W12 + (size_t)(3 * p) * NIN;
    float v;
    if (j == 0)      v = C11 * w[i]           + C12 * w[NIN + i];
    else if (j == 1) v = C12 * w[i]           + C11 * w[NIN + i];
    else             v = C33 * w[2 * NIN + i];
    unsigned short h = f2bf(v);
    g_Bhi[idx] = h;
    g_Blo[idx] = f2bf(v - bf2f(h));
}

// ---------------------------------------------------------------------------
// KX: x (fp32) -> bf16 into tiled A planes 0..3 (cols 0..127). Coalesced.
// ---------------------------------------------------------------------------
__global__ __launch_bounds__(256) void kx_split(const float* __restrict__ x)
{
    const int idx = blockIdx.x * 256 + threadIdx.x;   // NROWS*16
    const int row = idx >> 4, g = idx & 15;
    const float* src = x + (size_t)row * NF + g * 8;
    float4 v0 = ((const float4*)src)[0];
    float4 v1 = ((const float4*)src)[1];
    ushort8v h;
    h[0] = f2bf(v0.x); h[1] = f2bf(v0.y); h[2] = f2bf(v0.z); h[3] = f2bf(v0.w);
    h[4] = f2bf(v1.x); h[5] = f2bf(v1.y); h[6] = f2bf(v1.z); h[7] = f2bf(v1.w);
    *(ushort8v*)(g_Ahi + (size_t)(g >> 2) * PS + (size_t)row * 32 + (g & 3) * 8) = h;
}

// ---------------------------------------------------------------------------
// K1: jumps = leaky_relu(x @ W11^T + b11); d_new. fp32 GEMM.
// ---------------------------------------------------------------------------
__global__ __launch_bounds__(256, 2) void k1_fc11(
    const float* __restrict__ x, const float* __restrict__ W11,
    const float* __restrict__ b11, float* __restrict__ dnew)
{
    __shared__ float As[16][132];
    __shared__ float Bs[16][128];
    const int tid = threadIdx.x;
    const int row0 = blockIdx.x * 128;
    const int tx = tid & 15, ty = tid >> 4;

    float acc[8][8];
#pragma unroll
    for (int i = 0; i < 8; ++i)
#pragma unroll
        for (int j = 0; j < 8; ++j) acc[i][j] = 0.0f;

    const int lr = tid >> 2;
    const int lk = (tid & 3) * 4;
    const int bn = tid >> 1;
    const int bk = (tid & 1) * 8;

    for (int kc = 0; kc < 8; ++kc) {
        const int k0 = kc * 16;
        float4 a0 = *(const float4*)(x + (size_t)(row0 + lr) * NF + k0 + lk);
        float4 a1 = *(const float4*)(x + (size_t)(row0 + lr + 64) * NF + k0 + lk);
        float4 w0 = *(const float4*)(W11 + (size_t)bn * NF + k0 + bk);
        float4 w1 = *(const float4*)(W11 + (size_t)bn * NF + k0 + bk + 4);
        __syncthreads();
        As[lk+0][lr] = a0.x; As[lk+1][lr] = a0.y; As[lk+2][lr] = a0.z; As[lk+3][lr] = a0.w;
        As[lk+0][lr+64] = a1.x; As[lk+1][lr+64] = a1.y; As[lk+2][lr+64] = a1.z; As[lk+3][lr+64] = a1.w;
        Bs[bk+0][bn] = w0.x; Bs[bk+1][bn] = w0.y; Bs[bk+2][bn] = w0.z; Bs[bk+3][bn] = w0.w;
        Bs[bk+4][bn] = w1.x; Bs[bk+5][bn] = w1.y; Bs[bk+6][bn] = w1.z; Bs[bk+7][bn] = w1.w;
        __syncthreads();
#pragma unroll
        for (int k = 0; k < 16; ++k) {
            float4 av0 = *(const float4*)&As[k][8*ty];
            float4 av1 = *(const float4*)&As[k][8*ty+4];
            float4 bv0 = *(const float4*)&Bs[k][8*tx];
            float4 bv1 = *(const float4*)&Bs[k][8*tx+4];
            float a[8] = {av0.x,av0.y,av0.z,av0.w,av1.x,av1.y,av1.z,av1.w};
            float b[8] = {bv0.x,bv0.y,bv0.z,bv0.w,bv1.x,bv1.y,bv1.z,bv1.w};
#pragma unroll
            for (int i = 0; i < 8; ++i)
#pragma unroll
                for (int j = 0; j < 8; ++j)
                    acc[i][j] = fmaf(a[i], b[j], acc[i][j]);
        }
    }

#pragma unroll
    for (int i = 0; i < 8; ++i) {
        const int row = row0 + 8*ty + i;
        float dnv[4];
#pragma unroll
        for (int jp = 0; jp < 4; ++jp) {
            float z0 = acc[i][2*jp]   + b11[8*tx + 2*jp];
            float z1 = acc[i][2*jp+1] + b11[8*tx + 2*jp+1];
            float jn = fmaxf(z0, 0.0f);
            float js = (z1 > 0.0f) ? z1 : 0.01f * z1;
            float delta = sqrtf(jn*jn + js*js + 1e-12f);
            float dn = 0.1f * (delta - 0.01f) / (fmaxf(delta, 1e-12f) * 0.09f);
            dnv[jp] = fminf(fmaxf(dn, 0.0f), 1.0f);
        }
        float4 dv; dv.x = dnv[0]; dv.y = dnv[1]; dv.z = dnv[2]; dv.w = dnv[3];
        *(float4*)(dnew + (size_t)row * NCOH + 4*tx) = dv;
    }
}

// ---------------------------------------------------------------------------
// K2 (two-phase parallel cummax): k2a segment maxima, k2b carry + rewalk,
// emitting bf16 into tiled A planes 4..5.
// ---------------------------------------------------------------------------
__global__ __launch_bounds__(64) void k2a(const float* __restrict__ d,
                                          float* __restrict__ totals)
{
    const int b = blockIdx.x >> 3, seg = blockIdx.x & 7;
    const int c = threadIdx.x;
    const float* p = d + (size_t)b * NT * NCOH + (size_t)seg * 64 * NCOH + c;
    float m = 0.0f;
#pragma unroll 8
    for (int i = 0; i < 64; ++i) m = fmaxf(m, p[(size_t)i * NCOH]);
    totals[(size_t)(b * 8 + seg) * 64 + c] = m;
}

__global__ __launch_bounds__(64) void k2b(const float* __restrict__ d,
                                          const float* __restrict__ totals)
{
    const int b = blockIdx.x >> 3, seg = blockIdx.x & 7;
    const int c = threadIdx.x;
    float carry = 0.0f;
    for (int s = 0; s < seg; ++s)
        carry = fmaxf(carry, totals[(size_t)(b * 8 + s) * 64 + c]);
    const float* p = d + (size_t)b * NT * NCOH + (size_t)seg * 64 * NCOH + c;
    unsigned short* ah = g_Ahi + (size_t)(4 + (c >> 5)) * PS
                       + (size_t)(b * NT + seg * 64) * 32 + (c & 31);
    float m = carry;
#pragma unroll 8
    for (int i = 0; i < 64; ++i) {
        m = fmaxf(m, p[(size_t)i * NCOH]);
        ah[(size_t)i * 32] = f2bf(m);
    }
}

// ---------------------------------------------------------------------------
// K3: sig_tr = A @ B^T, A single bf16, B hi+lo. A-stationary, triple-buffered,
// vmcnt(6) + raw barrier, ONE barrier per chunk (6 total).
// R12: epilogue stores row-major into PADDED rows (chain p at col 4p+j).
// ---------------------------------------------------------------------------
__global__ __launch_bounds__(256) void k3_mfma(unsigned short* __restrict__ sig16)
{
    __shared__ unsigned short Ah[3][4096];   // 3 x 8 KB
    __shared__ unsigned short Bh[3][4096];
    __shared__ unsigned short Bl[3][4096];

    const int tid = threadIdx.x;
    const int lane = tid & 63, w = tid >> 6;
    const int m0 = blockIdx.y * 128;
    const int n0 = blockIdx.x * 128;
    const int wm = (w >> 1) * 64, wn = (w & 1) * 64;
    const int fr = lane & 15, fq = lane >> 4;

    f32x4 acc[4][4];
#pragma unroll
    for (int mi = 0; mi < 4; ++mi)
#pragma unroll
        for (int ni = 0; ni < 4; ++ni) acc[mi][ni] = (f32x4){0.f, 0.f, 0.f, 0.f};

    const int off0 = tid * 16;            // bytes [0, 4096)
    const int off1 = tid * 16 + 4096;     // bytes [4096, 8192)
    const int r0 = off0 >> 6, q0 = (off0 >> 4) & 3;   // B addressing
    const int r1 = off1 >> 6, q1 = (off1 >> 4) & 3;

    const char* Abase = (const char*)(g_Ahi + (size_t)m0 * 32);
    const size_t Aplane = PS * 2;         // bytes per plane

#define ISSUE_CHUNK(kc, buf_)                                                   \
    {                                                                           \
        const char* As_ = Abase + (size_t)(kc) * Aplane;                        \
        async_copy16(As_ + off0, (char*)Ah[buf_] + off0);                       \
        async_copy16(As_ + off1, (char*)Ah[buf_] + off1);                       \
        async_copy16(g_Bhi + (size_t)(n0 + r0) * NIN + (kc) * 32 + q0 * 8,      \
                     (char*)Bh[buf_] + off0);                                   \
        async_copy16(g_Bhi + (size_t)(n0 + r1) * NIN + (kc) * 32 + q1 * 8,      \
                     (char*)Bh[buf_] + off1);                                   \
        async_copy16(g_Blo + (size_t)(n0 + r0) * NIN + (kc) * 32 + q0 * 8,      \
                     (char*)Bl[buf_] + off0);                                   \
        async_copy16(g_Blo + (size_t)(n0 + r1) * NIN + (kc) * 32 + q1 * 8,      \
                     (char*)Bl[buf_] + off1);                                   \
    }

    ISSUE_CHUNK(0, 0);

    int buf = 0;
#pragma unroll 1
    for (int c = 0; c < 5; ++c) {
        const int nbuf = (buf == 2) ? 0 : buf + 1;
        ISSUE_CHUNK(c + 1, nbuf);
        WAITCNT_VM(6);
        __builtin_amdgcn_s_barrier();

        bf16x8 a[4], bh[4], bl[4];
#pragma unroll
        for (int mi = 0; mi < 4; ++mi)
            a[mi] = *(bf16x8*)&Ah[buf][(wm + mi * 16 + fr) * 32 + fq * 8];
#pragma unroll
        for (int ni = 0; ni < 4; ++ni) {
            bh[ni] = *(bf16x8*)&Bh[buf][(wn + ni * 16 + fr) * 32 + fq * 8];
            bl[ni] = *(bf16x8*)&Bl[buf][(wn + ni * 16 + fr) * 32 + fq * 8];
        }
#pragma unroll
        for (int mi = 0; mi < 4; ++mi)
#pragma unroll
            for (int ni = 0; ni < 4; ++ni) {
                acc[mi][ni] = __builtin_amdgcn_mfma_f32_16x16x32_bf16(
                    a[mi], bh[ni], acc[mi][ni], 0, 0, 0);
                acc[mi][ni] = __builtin_amdgcn_mfma_f32_16x16x32_bf16(
                    a[mi], bl[ni], acc[mi][ni], 0, 0, 0);
            }
        buf = nbuf;
    }

    WAITCNT_VM(0);
    __builtin_amdgcn_s_barrier();
    {
        bf16x8 a[4], bh[4], bl[4];
#pragma unroll
        for (int mi = 0; mi < 4; ++mi)
            a[mi] = *(bf16x8*)&Ah[buf][(wm + mi * 16 + fr) * 32 + fq * 8];
#pragma unroll
        for (int ni = 0; ni < 4; ++ni) {
            bh[ni] = *(bf16x8*)&Bh[buf][(wn + ni * 16 + fr) * 32 + fq * 8];
            bl[ni] = *(bf16x8*)&Bl[buf][(wn + ni * 16 + fr) * 32 + fq * 8];
        }
#pragma unroll
        for (int mi = 0; mi < 4; ++mi)
#pragma unroll
            for (int ni = 0; ni < 4; ++ni) {
                acc[mi][ni] = __builtin_amdgcn_mfma_f32_16x16x32_bf16(
                    a[mi], bh[ni], acc[mi][ni], 0, 0, 0);
                acc[mi][ni] = __builtin_amdgcn_mfma_f32_16x16x32_bf16(
                    a[mi], bl[ni], acc[mi][ni], 0, 0, 0);
            }
    }
#undef ISSUE_CHUNK

    // epilogue: C/D layout col=lane&15, row=(lane>>4)*4+reg; padded row store
    const int er = fq * 4, ec = fr;
#pragma unroll
    for (int ni = 0; ni < 4; ++ni) {
        const int col = n0 + wn + ni * 16 + ec;
        const int pch = col / 3, j = col - 3 * pch;
        const int pcol = pch * 4 + j;
#pragma unroll
        for (int mi = 0; mi < 4; ++mi)
#pragma unroll
            for (int r = 0; r < 4; ++r)
                sig16[(size_t)(m0 + wm + mi * 16 + er + r) * NBSP + pcol]
                    = f2bf(acc[mi][ni][r]);
    }
}

// ---------------------------------------------------------------------------
// K4: radial-return ep scan, in place on padded rows. ONE 8 B load + ONE 8 B
// store per t (vs 6 scalar VMEM in R10); wave-coalesced 512 B at fixed t;
// in-place stores hit warm L2 lines (no RFO — R11 lesson). depth-16 prefetch.
// ---------------------------------------------------------------------------
__global__ __launch_bounds__(128) void k4_plast(unsigned short* __restrict__ sig16)
{
    const int b = blockIdx.x;
    const int p = threadIdx.x;
    unsigned short* s = sig16 + (size_t)b * NT * NBSP + 4 * p;

    ushort4v buf[16];
#pragma unroll
    for (int u = 0; u < 16; ++u)
        buf[u] = *(const ushort4v*)(s + (size_t)u * NBSP);

    float ep = 0.0f;
#pragma unroll 16
    for (int t = 0; t < NT - 16; ++t) {
        const int sl = t & 15;
        ushort4v u = buf[sl];
        buf[sl] = *(const ushort4v*)(s + (size_t)(t + 16) * NBSP);
        float sxx = bf2f(u[0]), syy = bf2f(u[1]), txy = bf2f(u[2]);
        float seq = sqrtf(sxx*sxx - sxx*syy + syy*syy + 3.0f*txy*txy + 1e-12f);
        float fy = seq - (10.0f + 100.0f * ep);
        float dep = (fy > 0.0f) ? (fy / H3G) : 0.0f;
        ep += dep;
        float scale = (fy > 0.0f) ? ((10.0f + 100.0f * ep) / seq) : 1.0f;
        ushort4v o;
        o[0] = f2bf(sxx * scale); o[1] = f2bf(syy * scale);
        o[2] = f2bf(txy * scale); o[3] = 0;
        *(ushort4v*)(s + (size_t)t * NBSP) = o;
    }
#pragma unroll
    for (int t = NT - 16; t < NT; ++t) {
        ushort4v u = buf[t & 15];
        float sxx = bf2f(u[0]), syy = bf2f(u[1]), txy = bf2f(u[2]);
        float seq = sqrtf(sxx*sxx - sxx*syy + syy*syy + 3.0f*txy*txy + 1e-12f);
        float fy = seq - (10.0f + 100.0f * ep);
        float dep = (fy > 0.0f) ? (fy / H3G) : 0.0f;
        ep += dep;
        float scale = (fy > 0.0f) ? ((10.0f + 100.0f * ep) / seq) : 1.0f;
        ushort4v o;
        o[0] = f2bf(sxx * scale); o[1] = f2bf(syy * scale);
        o[2] = f2bf(txy * scale); o[3] = 0;
        *(ushort4v*)(s + (size_t)t * NBSP) = o;
    }
}

// ---------------------------------------------------------------------------
// K5: out = softplus(sig @ W2^T). Row-per-thread on padded rows: dense
// 512-wide dot vs zero-padded W2 in LDS (pads contribute 0).
// ---------------------------------------------------------------------------
__global__ __launch_bounds__(256) void k5_out(
    const unsigned short* __restrict__ sig16, const float* __restrict__ W2,
    float* __restrict__ out)
{
    __shared__ float W2s[6][NBSP];       // 12 KB, padded layout
    const int tid = threadIdx.x;
    for (int i = tid; i < 6 * NBSP; i += 256) {
        const int o = i / NBSP, c = i - o * NBSP;
        const int pch = c >> 2, j = c & 3;
        W2s[o][c] = (j < 3) ? W2[o * NBS + pch * 3 + j] : 0.0f;
    }
    __syncthreads();

    const int row = blockIdx.x * 256 + tid;
    const ushort8v* sv = (const ushort8v*)(sig16 + (size_t)row * NBSP);

    float acc[6] = {0, 0, 0, 0, 0, 0};
#pragma unroll 4
    for (int q = 0; q < NBSP / 8; ++q) {
        ushort8v u = sv[q];
        float v[8];
#pragma unroll
        for (int i = 0; i < 8; ++i) v[i] = bf2f(u[i]);
#pragma unroll
        for (int o = 0; o < 6; ++o) {
            float4 w0 = *(const float4*)&W2s[o][8 * q];
            float4 w1 = *(const float4*)&W2s[o][8 * q + 4];
            acc[o] = fmaf(v[0], w0.x, acc[o]); acc[o] = fmaf(v[1], w0.y, acc[o]);
            acc[o] = fmaf(v[2], w0.z, acc[o]); acc[o] = fmaf(v[3], w0.w, acc[o]);
            acc[o] = fmaf(v[4], w1.x, acc[o]); acc[o] = fmaf(v[5], w1.y, acc[o]);
            acc[o] = fmaf(v[6], w1.z, acc[o]); acc[o] = fmaf(v[7], w1.w, acc[o]);
        }
    }

    float res[6];
#pragma unroll
    for (int o = 0; o < 6; ++o) {
        float z = acc[o];
        res[o] = fmaxf(z, 0.0f) + log1pf(expf(-fabsf(z)));
    }
    float* op = out + (size_t)row * 6;
#pragma unroll
    for (int o = 0; o < 6; ++o) op[o] = res[o];
}

// ---------------------------------------------------------------------------
extern "C" void kernel_launch(void* const* d_in, const int* in_sizes, int n_in,
                              void* d_out, int out_size, void* d_ws, size_t ws_size,
                              hipStream_t stream)
{
    const float* x   = (const float*)d_in[0];
    const float* W11 = (const float*)d_in[1];
    const float* b11 = (const float*)d_in[2];
    const float* W12 = (const float*)d_in[3];
    const float* W2  = (const float*)d_in[4];
    float* out = (float*)d_out;

    // ws: dnew 32 MB @0 | sig16 (padded) 134.2 MB @32 MB | totals 512 KB @200 MB
    float* dnew = (float*)d_ws;
    unsigned short* sig16 = (unsigned short*)((char*)d_ws + (size_t)32 * 1024 * 1024);
    float* totals         = (float*)((char*)d_ws + (size_t)200 * 1024 * 1024);

    k0_w12<<<(NBS * NIN) / 256, 256, 0, stream>>>(W12);
    kx_split<<<(NROWS * 16) / 256, 256, 0, stream>>>(x);
    k1_fc11<<<NROWS / 128, 256, 0, stream>>>(x, W11, b11, dnew);
    k2a<<<NB * 8, 64, 0, stream>>>(dnew, totals);
    k2b<<<NB * 8, 64, 0, stream>>>(dnew, totals);
    k3_mfma<<<dim3(3, NROWS / 128), 256, 0, stream>>>(sig16);
    k4_plast<<<NB, 128, 0, stream>>>(sig16);
    k5_out<<<NROWS / 256, 256, 0, stream>>>(sig16, W2, out);
}